// Round 2
// baseline (256.675 us; speedup 1.0000x reference)
//
#include <hip/hip_runtime.h>

// Ranking-loss scalar reduction:
//   loss = 0.2 * (pos*sum_neg - neg*sum_pos) / (pos*neg)
// Needs sum(y), sum(y*lab), sum(lab) over N=32M floats/ints (256 MB read).
//
// R1: same-address fp64 atomics serialize -> per-block partials + stage2.
// R2/R3: three loop structures all pin at ~105us = 2.5 TB/s consumed ->
//   theory: L2 allocate path for zero-reuse stream.
// R4: __builtin_nontemporal_load -> reduce dropped below the 77us poison
//   fills (out of rocprof top-5), total 250.4us.
// R5: system-scope read-through (sc0 sc1 nt inline asm + vmcnt(0) drain
//   per iteration) -> total 251.8us, NEUTRAL. L2-allocate theory falsified
//   twice; cache policy is exonerated.
// R6 (this): revert to builtin nt loads (no forced drain) and specialize
//   the hot path to a COMPILE-TIME 4-iteration unroll (for N=32M every
//   block has exactly chunk=4096 f4 = 4 full spans), so the compiler can
//   software-pipeline loads across the whole 64KB-per-block stream under
//   the 64-VGPR cap. Also int (not long long) label counts. If this is
//   flat again, the pure-read stream is memory-system-pinned at ~3.8 TB/s
//   and the kernel is at its practical roofline (the remaining 155us of
//   the timed region is harness poison traffic at 87% HBM peak).
//
// fp64 accumulation of per-iteration fp32 partials: final expression is a
// catastrophic cancellation; fp32-partial error contributes ~1e-11 to the
// loss vs the 6e-7 harness threshold.

#define NBLK 2048
#define TPB 256
#define UNROLL 4

typedef float  f4 __attribute__((ext_vector_type(4)));
typedef int    i4 __attribute__((ext_vector_type(4)));

__global__ __launch_bounds__(TPB, 8)
void aux_loss_reduce(const float* __restrict__ y,
                     const int* __restrict__ lab,
                     double* __restrict__ part, int n) {
    const int n4 = n >> 2;
    const f4* __restrict__ y4 = (const f4*)y;
    const i4* __restrict__ l4 = (const i4*)lab;

    // contiguous chunk per block
    const int chunk = (n4 + NBLK - 1) / NBLK;          // 4096 for N=32M
    const int base = blockIdx.x * chunk;
    const int end = min(base + chunk, n4);
    const int span = TPB * UNROLL;
    const int nfull = (end - base) / span;             // full, bounds-check-free iters

    double s_all = 0.0, s_pos = 0.0;
    int cnt = 0;                                       // <= chunk*4/TPB = 64, fits int

#define BODY(i0_expr)                                                     \
    do {                                                                  \
        f4 v[UNROLL];                                                     \
        i4 l[UNROLL];                                                     \
        _Pragma("unroll")                                                 \
        for (int u = 0; u < UNROLL; ++u) {                                \
            const int i = (i0_expr) + u * TPB + (int)threadIdx.x;         \
            v[u] = __builtin_nontemporal_load(&y4[i]);                    \
            l[u] = __builtin_nontemporal_load(&l4[i]);                    \
        }                                                                 \
        float pa = 0.f, pp = 0.f;                                         \
        int pc = 0;                                                       \
        _Pragma("unroll")                                                 \
        for (int u = 0; u < UNROLL; ++u) {                                \
            pa += (v[u].x + v[u].y) + (v[u].z + v[u].w);                  \
            pp += (l[u].x ? v[u].x : 0.f) + (l[u].y ? v[u].y : 0.f)       \
                + (l[u].z ? v[u].z : 0.f) + (l[u].w ? v[u].w : 0.f);      \
            pc += l[u].x + l[u].y + l[u].z + l[u].w;                      \
        }                                                                 \
        s_all += (double)pa;                                              \
        s_pos += (double)pp;                                              \
        cnt += pc;                                                        \
    } while (0)

    int i0 = base;
    if (nfull == 4 && (end - base) == span * 4) {
        // Hot path for N=32M: compile-time trip count -> compiler is free
        // to software-pipeline all 32 nontemporal 16B loads per thread.
#pragma unroll
        for (int it = 0; it < 4; ++it) {
            BODY(base + it * span);
        }
        i0 = base + 4 * span;   // == end; remainder loop is a no-op
    } else {
        for (int it = 0; it < nfull; ++it, i0 += span) {
            BODY(i0);
        }
    }
#undef BODY

    // remainder iteration (bounds-checked) — no-op when chunk % span == 0
    for (int i = i0 + (int)threadIdx.x; i < end; i += TPB) {
        f4 v = __builtin_nontemporal_load(&y4[i]);
        i4 l = __builtin_nontemporal_load(&l4[i]);
        float pa = (v.x + v.y) + (v.z + v.w);
        float pp = (l.x ? v.x : 0.f) + (l.y ? v.y : 0.f)
                 + (l.z ? v.z : 0.f) + (l.w ? v.w : 0.f);
        s_all += (double)pa;
        s_pos += (double)pp;
        cnt += l.x + l.y + l.z + l.w;
    }

    // scalar tail (n % 4 elements) — block 0 only
    if (blockIdx.x == 0) {
        for (int j = (n4 << 2) + (int)threadIdx.x; j < n; j += TPB) {
            const float v = y[j];
            const int l = lab[j];
            s_all += (double)v;
            if (l) { s_pos += (double)v; cnt += l; }
        }
    }

    double c = (double)cnt;

    // wave-level reduce (64 lanes)
    for (int off = 32; off > 0; off >>= 1) {
        s_all += __shfl_down(s_all, off);
        s_pos += __shfl_down(s_pos, off);
        c     += __shfl_down(c, off);
    }

    // cross-wave via LDS (256-thread block = 4 waves)
    __shared__ double sh_all[4], sh_pos[4], sh_cnt[4];
    const int wave = threadIdx.x >> 6;
    const int lane = threadIdx.x & 63;
    if (lane == 0) { sh_all[wave] = s_all; sh_pos[wave] = s_pos; sh_cnt[wave] = c; }
    __syncthreads();

    if (threadIdx.x == 0) {
        double a = 0.0, p = 0.0, cc = 0.0;
        for (int w = 0; w < 4; ++w) { a += sh_all[w]; p += sh_pos[w]; cc += sh_cnt[w]; }
        // SoA partials: contention-free plain stores, coalesced stage-2 reads
        part[blockIdx.x]            = a;
        part[NBLK + blockIdx.x]     = p;
        part[2 * NBLK + blockIdx.x] = cc;
    }
}

__global__ void aux_loss_stage2(const double* __restrict__ part,
                                float* __restrict__ out, double n_total) {
    double a = 0.0, p = 0.0, cc = 0.0;
    for (int i = threadIdx.x; i < NBLK; i += blockDim.x) {
        a  += part[i];
        p  += part[NBLK + i];
        cc += part[2 * NBLK + i];
    }
    for (int off = 32; off > 0; off >>= 1) {
        a  += __shfl_down(a, off);
        p  += __shfl_down(p, off);
        cc += __shfl_down(cc, off);
    }
    __shared__ double sh_a[4], sh_p[4], sh_c[4];
    const int wave = threadIdx.x >> 6;
    const int lane = threadIdx.x & 63;
    if (lane == 0) { sh_a[wave] = a; sh_p[wave] = p; sh_c[wave] = cc; }
    __syncthreads();

    if (threadIdx.x == 0) {
        double sum_all = 0.0, sum_pos = 0.0, pos = 0.0;
        for (int w = 0; w < 4; ++w) { sum_all += sh_a[w]; sum_pos += sh_p[w]; pos += sh_c[w]; }
        const double neg = n_total - pos;
        const double sum_neg = sum_all - sum_pos;
        double loss = 0.0;
        if (pos > 0.0 && neg > 0.0) {
            loss = 0.2 * (pos * sum_neg - neg * sum_pos) / (pos * neg);
        }
        out[0] = (float)loss;
    }
}

extern "C" void kernel_launch(void* const* d_in, const int* in_sizes, int n_in,
                              void* d_out, int out_size, void* d_ws, size_t ws_size,
                              hipStream_t stream) {
    const float* y = (const float*)d_in[0];
    const int* lab = (const int*)d_in[1];
    int n = in_sizes[0];

    double* part = (double*)d_ws;  // 3 * NBLK doubles = 48 KB of scratch
    // No memset needed: every slot is unconditionally written by stage 1.

    aux_loss_reduce<<<NBLK, TPB, 0, stream>>>(y, lab, part, n);
    aux_loss_stage2<<<1, TPB, 0, stream>>>(part, (float*)d_out, (double)n);
}

// Round 3
// 251.837 us; speedup vs baseline: 1.0192x; 1.0192x over previous
//
#include <hip/hip_runtime.h>

// Ranking-loss scalar reduction:
//   loss = 0.2 * (pos*sum_neg - neg*sum_pos) / (pos*neg)
// Needs sum(y), sum(y*lab), sum(lab) over N=32M floats/ints (256 MB read).
//
// R1: same-address fp64 atomics serialize -> per-block partials + stage2.
// R2/R3: loop-structure variants all pin at ~105us (2.5 TB/s consumed).
// R4: __builtin_nontemporal_load -> reduce < 77us (below poison fills in
//   rocprof top-5), total 250.4us. Best so far.
// R5: system-scope read-through (sc0 sc1 nt + vmcnt(0) drain) -> 251.8us,
//   NEUTRAL. Cache-policy theory falsified.
// R6: compile-time 4-iter full unroll -> 256.7us, NEUTRAL-to-noise.
//   Pipelining theory falsified (and 64-VGPR cap forbids deep pipeline).
// R7 (this): concurrency test. Harness copyBuffer runs at 3.3 TB/s while
//   pure-write fills run 7.0 TB/s -> read path delivers ~half the write
//   rate system-wide, and our reduce (~3.4-3.8 TB/s inferred) already
//   matches the runtime's own read rate. Last untried lever: 2048 resident
//   blocks = 4096 concurrent sequential DRAM read streams (possible bank/
//   page thrash). NBLK 2048->512 (2 blocks/CU, 1MB contiguous chunk per
//   stream) cuts stream count 4x; MLP still over-covers latency >10x
//   (16 waves/CU x 8 x 1KB in flight). launch_bounds (256,4) -> 128 VGPRs
//   so all 8 loads + next addresses stay live.
//   If flat: declare roofline (kernel at parity with system copy engine's
//   read rate; 155us of the 250us total is harness poison traffic).
//
// fp64 accumulation of per-iteration fp32 partials: final expression is a
// catastrophic cancellation; fp32-partial error contributes ~1e-11 to the
// loss vs the 6e-7 harness threshold.

#define NBLK 512
#define TPB 256
#define UNROLL 4

typedef float  f4 __attribute__((ext_vector_type(4)));
typedef int    i4 __attribute__((ext_vector_type(4)));

__global__ __launch_bounds__(TPB, 4)
void aux_loss_reduce(const float* __restrict__ y,
                     const int* __restrict__ lab,
                     double* __restrict__ part, int n) {
    const int n4 = n >> 2;
    const f4* __restrict__ y4 = (const f4*)y;
    const i4* __restrict__ l4 = (const i4*)lab;

    // contiguous chunk per block: 16384 f4 = 1MB of y + 1MB of lab
    const int chunk = (n4 + NBLK - 1) / NBLK;
    const int base = blockIdx.x * chunk;
    const int end = min(base + chunk, n4);
    const int span = TPB * UNROLL;
    const int nfull = (end - base) / span;             // 16 for N=32M

    double s_all = 0.0, s_pos = 0.0;
    int cnt = 0;                                       // <= 4*chunk/TPB = 256, fits int

    int i0 = base;
    for (int it = 0; it < nfull; ++it, i0 += span) {
        f4 v[UNROLL];
        i4 l[UNROLL];
        // 8 independent nontemporal 16B loads in flight, contiguous 16KB block
#pragma unroll
        for (int u = 0; u < UNROLL; ++u) {
            const int i = i0 + u * TPB + (int)threadIdx.x;
            v[u] = __builtin_nontemporal_load(&y4[i]);
            l[u] = __builtin_nontemporal_load(&l4[i]);
        }
        float pa = 0.f, pp = 0.f;
        int pc = 0;
#pragma unroll
        for (int u = 0; u < UNROLL; ++u) {
            pa += (v[u].x + v[u].y) + (v[u].z + v[u].w);
            const float mx = l[u].x ? v[u].x : 0.f;
            const float my = l[u].y ? v[u].y : 0.f;
            const float mz = l[u].z ? v[u].z : 0.f;
            const float mw = l[u].w ? v[u].w : 0.f;
            pp += (mx + my) + (mz + mw);
            pc += l[u].x + l[u].y + l[u].z + l[u].w;
        }
        s_all += (double)pa;
        s_pos += (double)pp;
        cnt += pc;
    }
    // remainder iteration (bounds-checked) — no-op when chunk % span == 0
    for (int i = i0 + (int)threadIdx.x; i < end; i += TPB) {
        f4 v = __builtin_nontemporal_load(&y4[i]);
        i4 l = __builtin_nontemporal_load(&l4[i]);
        float pa = (v.x + v.y) + (v.z + v.w);
        float pp = (l.x ? v.x : 0.f) + (l.y ? v.y : 0.f)
                 + (l.z ? v.z : 0.f) + (l.w ? v.w : 0.f);
        s_all += (double)pa;
        s_pos += (double)pp;
        cnt += l.x + l.y + l.z + l.w;
    }

    // scalar tail (n % 4 elements) — block 0 only
    if (blockIdx.x == 0) {
        for (int j = (n4 << 2) + (int)threadIdx.x; j < n; j += TPB) {
            const float v = y[j];
            const int l = lab[j];
            s_all += (double)v;
            if (l) { s_pos += (double)v; cnt += l; }
        }
    }

    double c = (double)cnt;

    // wave-level reduce (64 lanes)
    for (int off = 32; off > 0; off >>= 1) {
        s_all += __shfl_down(s_all, off);
        s_pos += __shfl_down(s_pos, off);
        c     += __shfl_down(c, off);
    }

    // cross-wave via LDS (256-thread block = 4 waves)
    __shared__ double sh_all[4], sh_pos[4], sh_cnt[4];
    const int wave = threadIdx.x >> 6;
    const int lane = threadIdx.x & 63;
    if (lane == 0) { sh_all[wave] = s_all; sh_pos[wave] = s_pos; sh_cnt[wave] = c; }
    __syncthreads();

    if (threadIdx.x == 0) {
        double a = 0.0, p = 0.0, cc = 0.0;
        for (int w = 0; w < 4; ++w) { a += sh_all[w]; p += sh_pos[w]; cc += sh_cnt[w]; }
        // SoA partials: contention-free plain stores, coalesced stage-2 reads
        part[blockIdx.x]            = a;
        part[NBLK + blockIdx.x]     = p;
        part[2 * NBLK + blockIdx.x] = cc;
    }
}

__global__ void aux_loss_stage2(const double* __restrict__ part,
                                float* __restrict__ out, double n_total) {
    double a = 0.0, p = 0.0, cc = 0.0;
    for (int i = threadIdx.x; i < NBLK; i += blockDim.x) {
        a  += part[i];
        p  += part[NBLK + i];
        cc += part[2 * NBLK + i];
    }
    for (int off = 32; off > 0; off >>= 1) {
        a  += __shfl_down(a, off);
        p  += __shfl_down(p, off);
        cc += __shfl_down(cc, off);
    }
    __shared__ double sh_a[4], sh_p[4], sh_c[4];
    const int wave = threadIdx.x >> 6;
    const int lane = threadIdx.x & 63;
    if (lane == 0) { sh_a[wave] = a; sh_p[wave] = p; sh_c[wave] = cc; }
    __syncthreads();

    if (threadIdx.x == 0) {
        double sum_all = 0.0, sum_pos = 0.0, pos = 0.0;
        for (int w = 0; w < 4; ++w) { sum_all += sh_a[w]; sum_pos += sh_p[w]; pos += sh_c[w]; }
        const double neg = n_total - pos;
        const double sum_neg = sum_all - sum_pos;
        double loss = 0.0;
        if (pos > 0.0 && neg > 0.0) {
            loss = 0.2 * (pos * sum_neg - neg * sum_pos) / (pos * neg);
        }
        out[0] = (float)loss;
    }
}

extern "C" void kernel_launch(void* const* d_in, const int* in_sizes, int n_in,
                              void* d_out, int out_size, void* d_ws, size_t ws_size,
                              hipStream_t stream) {
    const float* y = (const float*)d_in[0];
    const int* lab = (const int*)d_in[1];
    int n = in_sizes[0];

    double* part = (double*)d_ws;  // 3 * NBLK doubles = 12 KB of scratch
    // No memset needed: every slot is unconditionally written by stage 1.

    aux_loss_reduce<<<NBLK, TPB, 0, stream>>>(y, lab, part, n);
    aux_loss_stage2<<<1, TPB, 0, stream>>>(part, (float*)d_out, (double)n);
}